// Round 21
// baseline (92.982 us; speedup 1.0000x reference)
//
#include <hip/hip_runtime.h>
#include <hip/hip_bf16.h>

#define NN 100000
#define NE 1600000
#define FIN 65
#define HID 128
#define NC 32
#define OUTC 65
#define NBUCK 391                     // ceil(NN / 256); bucket = dst >> 8
#define CHUNKS 400
#define CH 4000                       // edges per chunk; CHUNKS*CH == NE
#define ESTRIDE 5120                  // padded csrc slots per bucket
#define NODE_BLOCKS 1563              // ceil(NN / 64)

typedef __attribute__((ext_vector_type(8))) short s8v;    // 8 bf16 (4 VGPRs)
typedef __attribute__((ext_vector_type(4))) float f4v;    // MFMA accumulator
typedef __attribute__((ext_vector_type(2))) float f2v;
#define MFMA16(a, b, c) __builtin_amdgcn_mfma_f32_16x16x32_bf16(a, b, c, 0, 0, 0)

__device__ __forceinline__ float lrelu(float v){ return v > 0.f ? v : 0.2f * v; }
// round-to-nearest-even f32 -> bf16 bits (finite inputs)
__device__ __forceinline__ short f2bs(float f){
  unsigned u = __float_as_uint(f);
  u += 0x7fffu + ((u >> 16) & 1u);
  return (short)(u >> 16);
}
__device__ __forceinline__ float bfu_lo(unsigned u){ return __uint_as_float(u << 16); }
__device__ __forceinline__ float bfu_hi(unsigned u){ return __uint_as_float(u & 0xffff0000u); }
// f32 -> OCP fp8 e4m3 (HW convert, RNE)
__device__ __forceinline__ unsigned char f2fp8(float f){
  int p = __builtin_amdgcn_cvt_pk_fp8_f32(f, f, 0, false);
  return (unsigned char)(p & 0xff);
}
// inclusive Hillis-Steele scan over 512 LDS ints, 256 threads (all must call)
__device__ __forceinline__ void scan512incl(int* a){
  const int t = threadIdx.x;
  #pragma unroll
  for (int s = 1; s < 512; s <<= 1) {
    const int v0 = (t >= s) ? a[t - s] : 0;
    const int v1 = (t + 256 - s >= 0) ? a[t + 256 - s] : 0;
    __syncthreads();
    a[t] += v0;
    a[t + 256] += v1;
    __syncthreads();
  }
}

// ---------------------------------------------------------------------------
// Kernel 0: one-time frag-order weight transpose.
// ---------------------------------------------------------------------------
__global__ __launch_bounds__(256) void k_prep(
    const float* __restrict__ Wmlp, const float* __restrict__ W1,
    const float* __restrict__ W2, short* __restrict__ wbg)
{
  const int i = blockIdx.x * 256 + threadIdx.x;   // 0..8191
  {
    const int j = i & 7, l = (i >> 3) & 63, nt = (i >> 9) & 7, t = i >> 12;
    const int k = t * 32 + ((l >> 4) << 3) + j;
    const int col = (nt << 4) + (l & 15);
    wbg[i] = f2bs(Wmlp[k * HID + col]);
  }
  {
    const int j = i & 7, l = (i >> 3) & 63, nt = (i >> 9) & 3, t = i >> 11;
    const int k = t * 32 + ((l >> 4) << 3) + j;
    const int col = (nt << 4) + (l & 15);
    wbg[8192 + i] = f2bs(col < NC ? W1[k * NC + col] : W2[k * NC + col - NC]);
  }
}

// ---------------------------------------------------------------------------
// Kernel 1 (fused): blocks [0, NODE_BLOCKS) = MFMA front-end (R17);
// blocks [NODE_BLOCKS, +CHUNKS) = scatter v3: in-LDS bucket sort of the
// chunk's 4000 edges, then ONE contiguous 16 KB write + sequential table
// rows. Zero random global stores, zero global atomics.
// ---------------------------------------------------------------------------
__global__ __launch_bounds__(256) void k_main(
    const float* __restrict__ x, const short* __restrict__ wbg,
    const float* __restrict__ Wmlp, const float* __restrict__ bmlp,
    const float* __restrict__ a1s, const float* __restrict__ a1d,
    const float* __restrict__ a2s, const float* __restrict__ a2d,
    const int* __restrict__ ei,
    unsigned char* __restrict__ hb8,
    float* __restrict__ sd2, float* __restrict__ dd2,
    float* __restrict__ out,
    int* __restrict__ ebuf, int* __restrict__ cntT, int* __restrict__ offT)
{
  __shared__ alignas(16) char smem[20480];
  const int tid = threadIdx.x;

  if (blockIdx.x >= NODE_BLOCKS) {
    // ---------------- scatter branch v3: in-LDS bucket sort ----------------
    const int cb = blockIdx.x - NODE_BLOCKS;
    int* srt = (int*)smem;              // 4096 ints: sorted edges
    int* lh  = srt + 4096;              // 512 counts
    int* sc  = lh + 512;                // 512 scan / cursors
    for (int i = tid; i < 512; i += 256) lh[i] = 0;
    __syncthreads();

    const int4* s4 = (const int4*)ei + cb * (CH / 4);
    const int4* d4 = (const int4*)(ei + NE) + cb * (CH / 4);
    for (int i = tid; i < CH / 4; i += 256) {
      const int4 v = d4[i];
      atomicAdd(&lh[v.x >> 8], 1);
      atomicAdd(&lh[v.y >> 8], 1);
      atomicAdd(&lh[v.z >> 8], 1);
      atomicAdd(&lh[v.w >> 8], 1);
    }
    __syncthreads();
    for (int i = tid; i < 512; i += 256) sc[i] = lh[i];
    __syncthreads();
    scan512incl(sc);                    // inclusive sums
    // exclusive offsets -> tables ([chunk][bucket] = sequential writes)
    for (int i = tid; i < NBUCK; i += 256) {
      const int c = lh[i];
      const int ex = sc[i] - c;
      cntT[cb * NBUCK + i] = c;
      offT[cb * NBUCK + i] = ex;
      sc[i] = ex;                       // becomes placement cursor
    }
    __syncthreads();
    for (int i = tid; i < CH / 4; i += 256) {
      const int4 sv = s4[i];
      const int4 dv = d4[i];
      int b, r;
      b = dv.x >> 8; r = atomicAdd(&sc[b], 1); srt[r] = (sv.x << 8) | (dv.x & 255);
      b = dv.y >> 8; r = atomicAdd(&sc[b], 1); srt[r] = (sv.y << 8) | (dv.y & 255);
      b = dv.z >> 8; r = atomicAdd(&sc[b], 1); srt[r] = (sv.z << 8) | (dv.z & 255);
      b = dv.w >> 8; r = atomicAdd(&sc[b], 1); srt[r] = (sv.w << 8) | (dv.w & 255);
    }
    __syncthreads();
    // one contiguous, coalesced 16 KB stream-out
    for (int i = tid; i < CH; i += 256) ebuf[cb * CH + i] = srt[i];
    return;
  }

  // ---------------- node branch (MFMA front-end, R17) ----------------
  short* x0b = (short*)smem;                   // 64*136 bf16  17408 B
  float* w64 = (float*)(smem + 17408);         // 128
  float* bmv = (float*)(smem + 17920);         // 128
  float* avv = (float*)(smem + 18432);         // 128

  const int base = blockIdx.x * 64;
  const int w = tid >> 6, lane = tid & 63;
  const int g = lane >> 4, q = lane & 15;
  const int rowA = w * 16 + q;
  const int rowD0 = w * 16 + g * 4;
  const int nodeA = base + rowA;
  const s8v* wv8 = (const s8v*)wbg;

  // direct per-lane A-frag loads (16 independent scalar f32 loads)
  float xa[16];
  if (nodeA < NN) {
    const float* xr = x + (size_t)nodeA * FIN + g * 8;
    #pragma unroll
    for (int j = 0; j < 8; ++j) xa[j] = xr[j];
    #pragma unroll
    for (int j = 0; j < 8; ++j) xa[8 + j] = xr[32 + j];
  } else {
    #pragma unroll
    for (int j = 0; j < 16; ++j) xa[j] = 0.f;
  }
  // xc (col 64) per-lane direct loads
  float xc[4];
  #pragma unroll
  for (int r = 0; r < 4; ++r) {
    const int n2 = base + rowD0 + r;
    xc[r] = (n2 < NN) ? x[(size_t)n2 * FIN + 64] : 0.f;
  }
  // issue first stage-1 weight batch BEFORE the barrier
  s8v bb[8];
  #pragma unroll
  for (int nt = 0; nt < 8; ++nt) bb[nt] = wv8[nt * 64 + lane];

  // const staging (overlaps with the loads above)
  if (tid < 128) { w64[tid] = Wmlp[64 * HID + tid]; bmv[tid] = bmlp[tid]; }
  else if (tid < 160) {
    const int qq = tid - 128;
    avv[qq] = a1s[qq]; avv[32 + qq] = a1d[qq]; avv[64 + qq] = a2s[qq]; avv[96 + qq] = a2d[qq];
  }
  __syncthreads();

  s8v a0, a1;
  #pragma unroll
  for (int j = 0; j < 8; ++j) { a0[j] = f2bs(xa[j]); a1[j] = f2bs(xa[8 + j]); }

  // ---- stage 1: x0 = relu(x@Wmlp + b), batched loads (8 in flight) ----
  f4v acc[8];
  #pragma unroll
  for (int nt = 0; nt < 8; ++nt) acc[nt] = (f4v){0.f, 0.f, 0.f, 0.f};
  {
    #pragma unroll
    for (int nt = 0; nt < 8; ++nt) acc[nt] = MFMA16(a0, bb[nt], acc[nt]);
    #pragma unroll
    for (int nt = 0; nt < 8; ++nt) bb[nt] = wv8[(8 + nt) * 64 + lane];
    #pragma unroll
    for (int nt = 0; nt < 8; ++nt) acc[nt] = MFMA16(a1, bb[nt], acc[nt]);
  }

  float rmax[4] = {0.f, 0.f, 0.f, 0.f};
  #pragma unroll
  for (int nt = 0; nt < 8; ++nt) {
    const int col = nt * 16 + q;
    const float wvv = w64[col], bv = bmv[col];
    #pragma unroll
    for (int r = 0; r < 4; ++r) {
      const float v = fmaxf(fmaf(xc[r], wvv, acc[nt][r]) + bv, 0.f);
      rmax[r] = fmaxf(rmax[r], v);
      x0b[(rowD0 + r) * 136 + col] = f2bs(v);
    }
  }
  #pragma unroll
  for (int off = 1; off < 16; off <<= 1)
    #pragma unroll
    for (int r = 0; r < 4; ++r) rmax[r] = fmaxf(rmax[r], __shfl_xor(rmax[r], off));
  if (q == 0) {
    #pragma unroll
    for (int r = 0; r < 4; ++r) {
      const int node = base + rowD0 + r;
      if (node < NN) out[(size_t)node * OUTC + 64] = rmax[r];
    }
  }
  // x0b rows produced and consumed by the SAME wave -> no barrier needed.

  // ---- stage 2: h = x0 @ [W1|W2], batched loads (8 in flight) ----
  s8v af[4];
  #pragma unroll
  for (int t2 = 0; t2 < 4; ++t2)
    af[t2] = *(const s8v*)&x0b[rowA * 136 + t2 * 32 + g * 8];
  f4v hacc[4];
  #pragma unroll
  for (int nt = 0; nt < 4; ++nt) hacc[nt] = (f4v){0.f, 0.f, 0.f, 0.f};
  {
    s8v wt[8];
    #pragma unroll
    for (int i2 = 0; i2 < 8; ++i2) wt[i2] = wv8[1024 + i2 * 64 + lane];
    #pragma unroll
    for (int t2 = 0; t2 < 2; ++t2)
      #pragma unroll
      for (int nt = 0; nt < 4; ++nt)
        hacc[nt] = MFMA16(af[t2], wt[t2 * 4 + nt], hacc[nt]);
    #pragma unroll
    for (int i2 = 0; i2 < 8; ++i2) wt[i2] = wv8[1024 + (8 + i2) * 64 + lane];
    #pragma unroll
    for (int t2 = 0; t2 < 2; ++t2)
      #pragma unroll
      for (int nt = 0; nt < 4; ++nt)
        hacc[nt] = MFMA16(af[2 + t2], wt[t2 * 4 + nt], hacc[nt]);
  }

  // ---- epilogue ----
  float s1p[4], d1p[4], s2p[4], d2p[4];
  #pragma unroll
  for (int r = 0; r < 4; ++r) {
    s1p[r] = hacc[0][r] * avv[q]        + hacc[1][r] * avv[16 + q];
    d1p[r] = hacc[0][r] * avv[32 + q]   + hacc[1][r] * avv[48 + q];
    s2p[r] = hacc[2][r] * avv[64 + q]   + hacc[3][r] * avv[80 + q];
    d2p[r] = hacc[2][r] * avv[96 + q]   + hacc[3][r] * avv[112 + q];
  }
  #pragma unroll
  for (int off = 1; off < 16; off <<= 1) {
    #pragma unroll
    for (int r = 0; r < 4; ++r) {
      s1p[r] += __shfl_xor(s1p[r], off);
      d1p[r] += __shfl_xor(d1p[r], off);
      s2p[r] += __shfl_xor(s2p[r], off);
      d2p[r] += __shfl_xor(d2p[r], off);
    }
  }
  #pragma unroll
  for (int r = 0; r < 4; ++r) {
    const int node = base + rowD0 + r;
    if (node < NN) {
      #pragma unroll
      for (int nt = 0; nt < 4; ++nt)
        hb8[(size_t)node * 64 + nt * 16 + q] = f2fp8(hacc[nt][r]);
      if (q == 0) {
        *(float2*)&sd2[(size_t)node * 2] = make_float2(s1p[r], s2p[r]);
        *(float2*)&dd2[(size_t)node * 2] = make_float2(d1p[r], d2p[r]);
      }
    }
  }
}

// ---------------------------------------------------------------------------
// k_csr v3: one block per bucket. Gather the bucket's 400 chunk-segments
// (table-driven) into LDS, then per-dst histogram -> scan -> packed rpp +
// compact csrc (sequential writes within the bucket's padded window).
// ---------------------------------------------------------------------------
__global__ __launch_bounds__(256) void k_csr(
    const int* __restrict__ cntT, const int* __restrict__ offT,
    const int* __restrict__ ebuf,
    int* __restrict__ rpp, int* __restrict__ csrc)
{
  __shared__ int eL[4608];
  __shared__ int ccnt[512];
  __shared__ int cpos[512];
  __shared__ int coff[CHUNKS];
  __shared__ int lh[256];
  __shared__ int wsum[4];
  const int b = blockIdx.x;
  const int t = threadIdx.x;

  for (int i = t; i < 512; i += 256) {
    const int c = (i < CHUNKS) ? cntT[i * NBUCK + b] : 0;
    ccnt[i] = c;
    cpos[i] = c;
  }
  for (int i = t; i < CHUNKS; i += 256) coff[i] = offT[i * NBUCK + b];
  __syncthreads();
  scan512incl(cpos);                  // inclusive over chunks
  const int cntb = cpos[CHUNKS - 1];

  // gather chunk segments into eL (each thread owns chunks t, t+256)
  for (int c = t; c < CHUNKS; c += 256) {
    const int n = ccnt[c];
    const int dst0 = cpos[c] - n;
    const int src0 = c * CH + coff[c];
    for (int j = 0; j < n; ++j) eL[dst0 + j] = ebuf[src0 + j];
  }
  __syncthreads();

  // per-dst-local histogram
  lh[t] = 0;
  __syncthreads();
  for (int i = t; i < cntb; i += 256)
    atomicAdd(&lh[eL[i] & 255], 1);
  __syncthreads();

  const int lane = t & 63;
  const int wid = t >> 6;
  int v = lh[t];
  const int orig = v;
  for (int off = 1; off < 64; off <<= 1) {
    int tm = __shfl_up(v, off);
    if (lane >= off) v += tm;
  }
  if (lane == 63) wsum[wid] = v;
  __syncthreads();
  int add = 0;
  for (int ww = 0; ww < wid; ++ww) add += wsum[ww];
  const int ex = v + add - orig;

  const int nb0 = b << 8;
  const int e0 = b * ESTRIDE;
  if (nb0 + t < NN) rpp[nb0 + t] = ((e0 + ex) << 8) | orig;
  __syncthreads();
  lh[t] = ex;
  __syncthreads();
  for (int i = t; i < cntb; i += 256) {
    const int p = eL[i];
    const int r = atomicAdd(&lh[p & 255], 1);
    csrc[e0 + r] = ((unsigned)p) >> 8;
  }
}

// ---------------------------------------------------------------------------
// k_conv v12 (= v11 + Phase-A line prefetch). During Phase A each lane pulls
// one dword of ITS edge's hb8 row: one wave-instruction puts 64 lines in
// flight (vs 4 in the Phase-B pipeline), paying the fill latency once per
// 32-edge chunk. asm-keepalive prevents DCE (rule: ablation-via-skip DCEs).
// ---------------------------------------------------------------------------
__global__ __launch_bounds__(256) void k_conv(
    const int* __restrict__ rpp, const int* __restrict__ csrc,
    const unsigned char* __restrict__ hb8,
    const float* __restrict__ sd2, const float* __restrict__ dd2,
    const float* __restrict__ x,
    const float* __restrict__ b1, const float* __restrict__ b2,
    float* __restrict__ out)
{
  const int wid = threadIdx.x >> 6;
  const int lane = threadIdx.x & 63;
  const int half = lane >> 5;
  const int hl = lane & 31;
  const int eg = hl >> 4;            // edge-slot parity
  const int cg = hl & 15;            // channel group: channels 4cg..4cg+3
  const int conv = cg >> 3;          // 0: ch 0-31 (conv1), 1: ch 32-63 (conv2)

  const int node = blockIdx.x * 8 + wid * 2 + half;

  const int rv = rpp[node];
  const int base = ((unsigned)rv) >> 8;
  const int cnt = rv & 255;
  const float2 dnv = *(const float2*)&dd2[(size_t)node * 2];

  // hoist finalize inputs: these streams overlap the whole gather phase
  const int ch = cg * 4;
  const float* xr = x + (size_t)node * OUTC;
  float* row = out + (size_t)node * OUTC;
  const float4 xr4 = *(const float4*)&xr[ch];
  const float x64v = xr[64];
  const float o64 = row[64];                 // x3 from k_main
  const float4 bv = conv ? *(const float4*)&b2[ch - 32] : *(const float4*)&b1[ch];

  float a0 = 0.f, a1 = 0.f, a2 = 0.f, a3 = 0.f;
  float den = 0.f;

  for (int chunk = 0; chunk < cnt; chunk += 32) {
    const int rem = min(cnt - chunk, 32);

    // Phase A: parallel per-edge weight computation (edge = chunk + hl)
    // + line prefetch: lane hl pulls one dword of its edge's hb8 row,
    // putting up to 64 lines in flight in a single wave-instruction.
    int sE = 0;
    float w1v = 0.f, w2v = 0.f;
    if (hl < rem) {
      sE = csrc[base + chunk + hl];
      const unsigned pf = *(const unsigned*)(hb8 + ((size_t)sE << 6) + ((hl & 15) << 2));
      asm volatile("" :: "v"(pf));           // keep the prefetch alive
      const float2 sv = *(const float2*)&sd2[(size_t)sE * 2];
      w1v = __expf(lrelu(sv.x + dnv.x));
      w2v = __expf(lrelu(sv.y + dnv.y));
    }
    float d1 = w1v, d2 = w2v;
    #pragma unroll
    for (int off = 1; off < 32; off <<= 1) {
      d1 += __shfl_xor(d1, off);
      d2 += __shfl_xor(d2, off);
    }
    den += conv ? d2 : d1;

    // pack both conv weights as bf16 pair -> single shfl in Phase B
    const int wpk = (int)((((unsigned)(unsigned short)f2bs(w2v)) << 16) |
                           (unsigned)(unsigned short)f2bs(w1v));

    // Phase B: issue 4 gathers into arrays, then consume (loads all in flight)
    for (int i0 = 0; i0 < rem; i0 += 8) {
      unsigned wps[4];
      unsigned pvs[4];
      #pragma unroll
      for (int u = 0; u < 4; ++u) {
        const int i = i0 + u * 2 + eg;          // < 32 always
        const int src = half * 32 + i;
        const int s = __shfl(sE, src);
        wps[u] = (unsigned)__shfl(wpk, src);
        pvs[u] = *(const unsigned*)(hb8 + ((size_t)s << 6) + cg * 4);
      }
      #pragma unroll
      for (int u = 0; u < 4; ++u) {
        const float w = conv ? bfu_hi(wps[u]) : bfu_lo(wps[u]);
        const f2v lo = __builtin_amdgcn_cvt_pk_f32_fp8((int)pvs[u], false);
        const f2v hi = __builtin_amdgcn_cvt_pk_f32_fp8((int)pvs[u], true);
        a0 = fmaf(w, lo[0], a0);
        a1 = fmaf(w, lo[1], a1);
        a2 = fmaf(w, hi[0], a2);
        a3 = fmaf(w, hi[1], a3);
      }
    }
  }

  // fold edge parity
  a0 += __shfl_xor(a0, 16);
  a1 += __shfl_xor(a1, 16);
  a2 += __shfl_xor(a2, 16);
  a3 += __shfl_xor(a3, 16);

  // ---- fused finalize ----
  const float rden = 1.f / (den + 1e-16f);
  float v0 = a0 * rden + bv.x;
  float v1 = a1 * rden + bv.y;
  float v2 = a2 * rden + bv.z;
  float v3 = a3 * rden + bv.w;
  if (conv == 0) {
    v0 = fmaxf(v0, 0.f);
    v1 = fmaxf(v1, 0.f);
    v2 = fmaxf(v2, 0.f);
    v3 = fmaxf(v3, 0.f);
  }
  v0 += xr4.x; v1 += xr4.y; v2 += xr4.z; v3 += xr4.w;
  const float v64 = o64 + x64v;

  float mx = fmaxf(fmaxf(v0, v1), fmaxf(v2, v3));
  #pragma unroll
  for (int off = 1; off < 16; off <<= 1) mx = fmaxf(mx, __shfl_xor(mx, off));
  mx = fmaxf(mx, v64);
  float sm = __expf(v0 - mx) + __expf(v1 - mx) + __expf(v2 - mx) + __expf(v3 - mx);
  #pragma unroll
  for (int off = 1; off < 16; off <<= 1) sm += __shfl_xor(sm, off);
  sm += __expf(v64 - mx);
  const float ls = __logf(sm);

  if (eg == 0) {
    *(float4*)&row[ch] = make_float4(v0 - mx - ls, v1 - mx - ls, v2 - mx - ls, v3 - mx - ls);
    if (hl == 0) row[64] = v64 - mx - ls;
  }
}

// ---------------------------------------------------------------------------
extern "C" void kernel_launch(void* const* d_in, const int* in_sizes, int n_in,
                              void* d_out, int out_size, void* d_ws, size_t ws_size,
                              hipStream_t stream)
{
  const float* x    = (const float*)d_in[0];
  const int*   ei   = (const int*)d_in[1];
  const float* Wmlp = (const float*)d_in[2];
  const float* bmlp = (const float*)d_in[3];
  const float* W1   = (const float*)d_in[4];
  const float* a1s  = (const float*)d_in[5];
  const float* a1d  = (const float*)d_in[6];
  const float* b1   = (const float*)d_in[7];
  const float* W2   = (const float*)d_in[8];
  const float* a2s  = (const float*)d_in[9];
  const float* a2d  = (const float*)d_in[10];
  const float* b2   = (const float*)d_in[11];
  float* out = (float*)d_out;

  unsigned char* hb8 = (unsigned char*)d_ws;             // NN*64 fp8 (6.4 MB)
  float* sd2 = (float*)(hb8 + (size_t)NN * 64);          // 2*NN
  float* dd2 = sd2 + (size_t)2 * NN;                     // 2*NN
  int* ebuf   = (int*)(dd2 + (size_t)2 * NN);            // NE (6.4 MB, chunk-major sorted)
  int* csrc   = ebuf + NE;                               // NBUCK*ESTRIDE (8 MB)
  int* rpp    = csrc + (size_t)NBUCK * ESTRIDE;          // NBUCK*256
  int* cntT   = rpp + NBUCK * 256;                       // CHUNKS*NBUCK
  int* offT   = cntT + CHUNKS * NBUCK;                   // CHUNKS*NBUCK
  short* wbg  = (short*)(offT + CHUNKS * NBUCK);         // 16384 bf16

  k_prep<<<32, 256, 0, stream>>>(Wmlp, W1, W2, wbg);

  k_main<<<NODE_BLOCKS + CHUNKS, 256, 0, stream>>>(
      x, wbg, Wmlp, bmlp, a1s, a1d, a2s, a2d, ei,
      hb8, sd2, dd2, out, ebuf, cntT, offT);

  k_csr<<<NBUCK, 256, 0, stream>>>(cntT, offT, ebuf, rpp, csrc);

  k_conv<<<NN / 8, 256, 0, stream>>>(rpp, csrc, hb8, sd2, dd2, x, b1, b2, out);
}

// Round 22
// 88.144 us; speedup vs baseline: 1.0549x; 1.0549x over previous
//
#include <hip/hip_runtime.h>
#include <hip/hip_bf16.h>

#define NN 100000
#define NE 1600000
#define FIN 65
#define HID 128
#define NC 32
#define OUTC 65
#define NBUCK 391                     // ceil(NN / 256); bucket = dst >> 8
#define CHUNKS 400
#define CH 4000                       // edges per chunk; CHUNKS*CH == NE
#define ESTRIDE 5120                  // padded csrc slots per bucket
#define NODE_BLOCKS 1563              // ceil(NN / 64)

typedef __attribute__((ext_vector_type(8))) short s8v;    // 8 bf16 (4 VGPRs)
typedef __attribute__((ext_vector_type(4))) float f4v;    // MFMA accumulator
typedef __attribute__((ext_vector_type(2))) float f2v;
#define MFMA16(a, b, c) __builtin_amdgcn_mfma_f32_16x16x32_bf16(a, b, c, 0, 0, 0)

__device__ __forceinline__ float lrelu(float v){ return v > 0.f ? v : 0.2f * v; }
// round-to-nearest-even f32 -> bf16 bits (finite inputs)
__device__ __forceinline__ short f2bs(float f){
  unsigned u = __float_as_uint(f);
  u += 0x7fffu + ((u >> 16) & 1u);
  return (short)(u >> 16);
}
__device__ __forceinline__ float bfu_lo(unsigned u){ return __uint_as_float(u << 16); }
__device__ __forceinline__ float bfu_hi(unsigned u){ return __uint_as_float(u & 0xffff0000u); }
// f32 -> OCP fp8 e4m3 (HW convert, RNE)
__device__ __forceinline__ unsigned char f2fp8(float f){
  int p = __builtin_amdgcn_cvt_pk_fp8_f32(f, f, 0, false);
  return (unsigned char)(p & 0xff);
}
// inclusive Hillis-Steele scan over 512 LDS ints, 256 threads (all must call)
__device__ __forceinline__ void scan512incl(int* a){
  const int t = threadIdx.x;
  #pragma unroll
  for (int s = 1; s < 512; s <<= 1) {
    const int v0 = (t >= s) ? a[t - s] : 0;
    const int v1 = (t + 256 - s >= 0) ? a[t + 256 - s] : 0;
    __syncthreads();
    a[t] += v0;
    a[t + 256] += v1;
    __syncthreads();
  }
}

// ---------------------------------------------------------------------------
// Kernel 0: one-time frag-order weight transpose.
// ---------------------------------------------------------------------------
__global__ __launch_bounds__(256) void k_prep(
    const float* __restrict__ Wmlp, const float* __restrict__ W1,
    const float* __restrict__ W2, short* __restrict__ wbg)
{
  const int i = blockIdx.x * 256 + threadIdx.x;   // 0..8191
  {
    const int j = i & 7, l = (i >> 3) & 63, nt = (i >> 9) & 7, t = i >> 12;
    const int k = t * 32 + ((l >> 4) << 3) + j;
    const int col = (nt << 4) + (l & 15);
    wbg[i] = f2bs(Wmlp[k * HID + col]);
  }
  {
    const int j = i & 7, l = (i >> 3) & 63, nt = (i >> 9) & 3, t = i >> 11;
    const int k = t * 32 + ((l >> 4) << 3) + j;
    const int col = (nt << 4) + (l & 15);
    wbg[8192 + i] = f2bs(col < NC ? W1[k * NC + col] : W2[k * NC + col - NC]);
  }
}

// ---------------------------------------------------------------------------
// Kernel 1 (fused): blocks [0, NODE_BLOCKS) = MFMA front-end;
// blocks [NODE_BLOCKS, +CHUNKS) = scatter v3: in-LDS bucket sort of the
// chunk's 4000 edges, then ONE contiguous 16 KB write + sequential table
// rows. Zero random global stores, zero global atomics.
// ---------------------------------------------------------------------------
__global__ __launch_bounds__(256) void k_main(
    const float* __restrict__ x, const short* __restrict__ wbg,
    const float* __restrict__ Wmlp, const float* __restrict__ bmlp,
    const float* __restrict__ a1s, const float* __restrict__ a1d,
    const float* __restrict__ a2s, const float* __restrict__ a2d,
    const int* __restrict__ ei,
    unsigned char* __restrict__ hb8,
    float* __restrict__ sd2, float* __restrict__ dd2,
    float* __restrict__ out,
    int* __restrict__ ebuf, int* __restrict__ cntT, int* __restrict__ offT)
{
  __shared__ alignas(16) char smem[20480];
  const int tid = threadIdx.x;

  if (blockIdx.x >= NODE_BLOCKS) {
    // ---------------- scatter branch v3: in-LDS bucket sort ----------------
    const int cb = blockIdx.x - NODE_BLOCKS;
    int* srt = (int*)smem;              // 4096 ints: sorted edges
    int* lh  = srt + 4096;              // 512 counts
    int* sc  = lh + 512;                // 512 scan / cursors
    for (int i = tid; i < 512; i += 256) lh[i] = 0;
    __syncthreads();

    const int4* s4 = (const int4*)ei + cb * (CH / 4);
    const int4* d4 = (const int4*)(ei + NE) + cb * (CH / 4);
    for (int i = tid; i < CH / 4; i += 256) {
      const int4 v = d4[i];
      atomicAdd(&lh[v.x >> 8], 1);
      atomicAdd(&lh[v.y >> 8], 1);
      atomicAdd(&lh[v.z >> 8], 1);
      atomicAdd(&lh[v.w >> 8], 1);
    }
    __syncthreads();
    for (int i = tid; i < 512; i += 256) sc[i] = lh[i];
    __syncthreads();
    scan512incl(sc);                    // inclusive sums
    // exclusive offsets -> tables ([chunk][bucket] = sequential writes)
    for (int i = tid; i < NBUCK; i += 256) {
      const int c = lh[i];
      const int ex = sc[i] - c;
      cntT[cb * NBUCK + i] = c;
      offT[cb * NBUCK + i] = ex;
      sc[i] = ex;                       // becomes placement cursor
    }
    __syncthreads();
    for (int i = tid; i < CH / 4; i += 256) {
      const int4 sv = s4[i];
      const int4 dv = d4[i];
      int b, r;
      b = dv.x >> 8; r = atomicAdd(&sc[b], 1); srt[r] = (sv.x << 8) | (dv.x & 255);
      b = dv.y >> 8; r = atomicAdd(&sc[b], 1); srt[r] = (sv.y << 8) | (dv.y & 255);
      b = dv.z >> 8; r = atomicAdd(&sc[b], 1); srt[r] = (sv.z << 8) | (dv.z & 255);
      b = dv.w >> 8; r = atomicAdd(&sc[b], 1); srt[r] = (sv.w << 8) | (dv.w & 255);
    }
    __syncthreads();
    // one contiguous, coalesced 16 KB stream-out
    for (int i = tid; i < CH; i += 256) ebuf[cb * CH + i] = srt[i];
    return;
  }

  // ---------------- node branch (MFMA front-end) ----------------
  short* x0b = (short*)smem;                   // 64*136 bf16  17408 B
  float* w64 = (float*)(smem + 17408);         // 128
  float* bmv = (float*)(smem + 17920);         // 128
  float* avv = (float*)(smem + 18432);         // 128

  const int base = blockIdx.x * 64;
  const int w = tid >> 6, lane = tid & 63;
  const int g = lane >> 4, q = lane & 15;
  const int rowA = w * 16 + q;
  const int rowD0 = w * 16 + g * 4;
  const int nodeA = base + rowA;
  const s8v* wv8 = (const s8v*)wbg;

  // direct per-lane A-frag loads (16 independent scalar f32 loads)
  float xa[16];
  if (nodeA < NN) {
    const float* xr = x + (size_t)nodeA * FIN + g * 8;
    #pragma unroll
    for (int j = 0; j < 8; ++j) xa[j] = xr[j];
    #pragma unroll
    for (int j = 0; j < 8; ++j) xa[8 + j] = xr[32 + j];
  } else {
    #pragma unroll
    for (int j = 0; j < 16; ++j) xa[j] = 0.f;
  }
  // xc (col 64) per-lane direct loads
  float xc[4];
  #pragma unroll
  for (int r = 0; r < 4; ++r) {
    const int n2 = base + rowD0 + r;
    xc[r] = (n2 < NN) ? x[(size_t)n2 * FIN + 64] : 0.f;
  }
  // issue first stage-1 weight batch BEFORE the barrier
  s8v bb[8];
  #pragma unroll
  for (int nt = 0; nt < 8; ++nt) bb[nt] = wv8[nt * 64 + lane];

  // const staging (overlaps with the loads above)
  if (tid < 128) { w64[tid] = Wmlp[64 * HID + tid]; bmv[tid] = bmlp[tid]; }
  else if (tid < 160) {
    const int qq = tid - 128;
    avv[qq] = a1s[qq]; avv[32 + qq] = a1d[qq]; avv[64 + qq] = a2s[qq]; avv[96 + qq] = a2d[qq];
  }
  __syncthreads();

  s8v a0, a1;
  #pragma unroll
  for (int j = 0; j < 8; ++j) { a0[j] = f2bs(xa[j]); a1[j] = f2bs(xa[8 + j]); }

  // ---- stage 1: x0 = relu(x@Wmlp + b), batched loads (8 in flight) ----
  f4v acc[8];
  #pragma unroll
  for (int nt = 0; nt < 8; ++nt) acc[nt] = (f4v){0.f, 0.f, 0.f, 0.f};
  {
    #pragma unroll
    for (int nt = 0; nt < 8; ++nt) acc[nt] = MFMA16(a0, bb[nt], acc[nt]);
    #pragma unroll
    for (int nt = 0; nt < 8; ++nt) bb[nt] = wv8[(8 + nt) * 64 + lane];
    #pragma unroll
    for (int nt = 0; nt < 8; ++nt) acc[nt] = MFMA16(a1, bb[nt], acc[nt]);
  }

  float rmax[4] = {0.f, 0.f, 0.f, 0.f};
  #pragma unroll
  for (int nt = 0; nt < 8; ++nt) {
    const int col = nt * 16 + q;
    const float wvv = w64[col], bv = bmv[col];
    #pragma unroll
    for (int r = 0; r < 4; ++r) {
      const float v = fmaxf(fmaf(xc[r], wvv, acc[nt][r]) + bv, 0.f);
      rmax[r] = fmaxf(rmax[r], v);
      x0b[(rowD0 + r) * 136 + col] = f2bs(v);
    }
  }
  #pragma unroll
  for (int off = 1; off < 16; off <<= 1)
    #pragma unroll
    for (int r = 0; r < 4; ++r) rmax[r] = fmaxf(rmax[r], __shfl_xor(rmax[r], off));
  if (q == 0) {
    #pragma unroll
    for (int r = 0; r < 4; ++r) {
      const int node = base + rowD0 + r;
      if (node < NN) out[(size_t)node * OUTC + 64] = rmax[r];
    }
  }
  // x0b rows produced and consumed by the SAME wave -> no barrier needed.

  // ---- stage 2: h = x0 @ [W1|W2], batched loads (8 in flight) ----
  s8v af[4];
  #pragma unroll
  for (int t2 = 0; t2 < 4; ++t2)
    af[t2] = *(const s8v*)&x0b[rowA * 136 + t2 * 32 + g * 8];
  f4v hacc[4];
  #pragma unroll
  for (int nt = 0; nt < 4; ++nt) hacc[nt] = (f4v){0.f, 0.f, 0.f, 0.f};
  {
    s8v wt[8];
    #pragma unroll
    for (int i2 = 0; i2 < 8; ++i2) wt[i2] = wv8[1024 + i2 * 64 + lane];
    #pragma unroll
    for (int t2 = 0; t2 < 2; ++t2)
      #pragma unroll
      for (int nt = 0; nt < 4; ++nt)
        hacc[nt] = MFMA16(af[t2], wt[t2 * 4 + nt], hacc[nt]);
    #pragma unroll
    for (int i2 = 0; i2 < 8; ++i2) wt[i2] = wv8[1024 + (8 + i2) * 64 + lane];
    #pragma unroll
    for (int t2 = 0; t2 < 2; ++t2)
      #pragma unroll
      for (int nt = 0; nt < 4; ++nt)
        hacc[nt] = MFMA16(af[2 + t2], wt[t2 * 4 + nt], hacc[nt]);
  }

  // ---- epilogue ----
  float s1p[4], d1p[4], s2p[4], d2p[4];
  #pragma unroll
  for (int r = 0; r < 4; ++r) {
    s1p[r] = hacc[0][r] * avv[q]        + hacc[1][r] * avv[16 + q];
    d1p[r] = hacc[0][r] * avv[32 + q]   + hacc[1][r] * avv[48 + q];
    s2p[r] = hacc[2][r] * avv[64 + q]   + hacc[3][r] * avv[80 + q];
    d2p[r] = hacc[2][r] * avv[96 + q]   + hacc[3][r] * avv[112 + q];
  }
  #pragma unroll
  for (int off = 1; off < 16; off <<= 1) {
    #pragma unroll
    for (int r = 0; r < 4; ++r) {
      s1p[r] += __shfl_xor(s1p[r], off);
      d1p[r] += __shfl_xor(d1p[r], off);
      s2p[r] += __shfl_xor(s2p[r], off);
      d2p[r] += __shfl_xor(d2p[r], off);
    }
  }
  #pragma unroll
  for (int r = 0; r < 4; ++r) {
    const int node = base + rowD0 + r;
    if (node < NN) {
      #pragma unroll
      for (int nt = 0; nt < 4; ++nt)
        hb8[(size_t)node * 64 + nt * 16 + q] = f2fp8(hacc[nt][r]);
      if (q == 0) {
        *(float2*)&sd2[(size_t)node * 2] = make_float2(s1p[r], s2p[r]);
        *(float2*)&dd2[(size_t)node * 2] = make_float2(d1p[r], d2p[r]);
      }
    }
  }
}

// ---------------------------------------------------------------------------
// k_csr v3: one block per bucket. Gather the bucket's 400 chunk-segments
// (table-driven) into LDS, then per-dst histogram -> scan -> packed rpp +
// compact csrc (sequential writes within the bucket's padded window).
// ---------------------------------------------------------------------------
__global__ __launch_bounds__(256) void k_csr(
    const int* __restrict__ cntT, const int* __restrict__ offT,
    const int* __restrict__ ebuf,
    int* __restrict__ rpp, int* __restrict__ csrc)
{
  __shared__ int eL[4608];
  __shared__ int ccnt[512];
  __shared__ int cpos[512];
  __shared__ int coff[CHUNKS];
  __shared__ int lh[256];
  __shared__ int wsum[4];
  const int b = blockIdx.x;
  const int t = threadIdx.x;

  for (int i = t; i < 512; i += 256) {
    const int c = (i < CHUNKS) ? cntT[i * NBUCK + b] : 0;
    ccnt[i] = c;
    cpos[i] = c;
  }
  for (int i = t; i < CHUNKS; i += 256) coff[i] = offT[i * NBUCK + b];
  __syncthreads();
  scan512incl(cpos);                  // inclusive over chunks
  const int cntb = cpos[CHUNKS - 1];

  // gather chunk segments into eL (each thread owns chunks t, t+256)
  for (int c = t; c < CHUNKS; c += 256) {
    const int n = ccnt[c];
    const int dst0 = cpos[c] - n;
    const int src0 = c * CH + coff[c];
    for (int j = 0; j < n; ++j) eL[dst0 + j] = ebuf[src0 + j];
  }
  __syncthreads();

  // per-dst-local histogram
  lh[t] = 0;
  __syncthreads();
  for (int i = t; i < cntb; i += 256)
    atomicAdd(&lh[eL[i] & 255], 1);
  __syncthreads();

  const int lane = t & 63;
  const int wid = t >> 6;
  int v = lh[t];
  const int orig = v;
  for (int off = 1; off < 64; off <<= 1) {
    int tm = __shfl_up(v, off);
    if (lane >= off) v += tm;
  }
  if (lane == 63) wsum[wid] = v;
  __syncthreads();
  int add = 0;
  for (int ww = 0; ww < wid; ++ww) add += wsum[ww];
  const int ex = v + add - orig;

  const int nb0 = b << 8;
  const int e0 = b * ESTRIDE;
  if (nb0 + t < NN) rpp[nb0 + t] = ((e0 + ex) << 8) | orig;
  __syncthreads();
  lh[t] = ex;
  __syncthreads();
  for (int i = t; i < cntb; i += 256) {
    const int p = eL[i];
    const int r = atomicAdd(&lh[p & 255], 1);
    csrc[e0 + r] = ((unsigned)p) >> 8;
  }
}

// ---------------------------------------------------------------------------
// k_conv v11 (measured best, R20): 2 nodes/wave, Phase-A parallel weights,
// Phase-B issue/consume gather pipeline, hoisted finalize loads, fp8 h rows.
// ---------------------------------------------------------------------------
__global__ __launch_bounds__(256) void k_conv(
    const int* __restrict__ rpp, const int* __restrict__ csrc,
    const unsigned char* __restrict__ hb8,
    const float* __restrict__ sd2, const float* __restrict__ dd2,
    const float* __restrict__ x,
    const float* __restrict__ b1, const float* __restrict__ b2,
    float* __restrict__ out)
{
  const int wid = threadIdx.x >> 6;
  const int lane = threadIdx.x & 63;
  const int half = lane >> 5;
  const int hl = lane & 31;
  const int eg = hl >> 4;            // edge-slot parity
  const int cg = hl & 15;            // channel group: channels 4cg..4cg+3
  const int conv = cg >> 3;          // 0: ch 0-31 (conv1), 1: ch 32-63 (conv2)

  const int node = blockIdx.x * 8 + wid * 2 + half;

  const int rv = rpp[node];
  const int base = ((unsigned)rv) >> 8;
  const int cnt = rv & 255;
  const float2 dnv = *(const float2*)&dd2[(size_t)node * 2];

  // hoist finalize inputs: these streams overlap the whole gather phase
  const int ch = cg * 4;
  const float* xr = x + (size_t)node * OUTC;
  float* row = out + (size_t)node * OUTC;
  const float4 xr4 = *(const float4*)&xr[ch];
  const float x64v = xr[64];
  const float o64 = row[64];                 // x3 from k_main
  const float4 bv = conv ? *(const float4*)&b2[ch - 32] : *(const float4*)&b1[ch];

  float a0 = 0.f, a1 = 0.f, a2 = 0.f, a3 = 0.f;
  float den = 0.f;

  for (int chunk = 0; chunk < cnt; chunk += 32) {
    const int rem = min(cnt - chunk, 32);

    // Phase A: parallel per-edge weight computation (edge = chunk + hl)
    int sE = 0;
    float w1v = 0.f, w2v = 0.f;
    if (hl < rem) {
      sE = csrc[base + chunk + hl];
      const float2 sv = *(const float2*)&sd2[(size_t)sE * 2];
      w1v = __expf(lrelu(sv.x + dnv.x));
      w2v = __expf(lrelu(sv.y + dnv.y));
    }
    float d1 = w1v, d2 = w2v;
    #pragma unroll
    for (int off = 1; off < 32; off <<= 1) {
      d1 += __shfl_xor(d1, off);
      d2 += __shfl_xor(d2, off);
    }
    den += conv ? d2 : d1;

    // pack both conv weights as bf16 pair -> single shfl in Phase B
    const int wpk = (int)((((unsigned)(unsigned short)f2bs(w2v)) << 16) |
                           (unsigned)(unsigned short)f2bs(w1v));

    // Phase B: issue 4 gathers into arrays, then consume (loads all in flight)
    for (int i0 = 0; i0 < rem; i0 += 8) {
      unsigned wps[4];
      unsigned pvs[4];
      #pragma unroll
      for (int u = 0; u < 4; ++u) {
        const int i = i0 + u * 2 + eg;          // < 32 always
        const int src = half * 32 + i;
        const int s = __shfl(sE, src);
        wps[u] = (unsigned)__shfl(wpk, src);
        pvs[u] = *(const unsigned*)(hb8 + ((size_t)s << 6) + cg * 4);
      }
      #pragma unroll
      for (int u = 0; u < 4; ++u) {
        const float w = conv ? bfu_hi(wps[u]) : bfu_lo(wps[u]);
        const f2v lo = __builtin_amdgcn_cvt_pk_f32_fp8((int)pvs[u], false);
        const f2v hi = __builtin_amdgcn_cvt_pk_f32_fp8((int)pvs[u], true);
        a0 = fmaf(w, lo[0], a0);
        a1 = fmaf(w, lo[1], a1);
        a2 = fmaf(w, hi[0], a2);
        a3 = fmaf(w, hi[1], a3);
      }
    }
  }

  // fold edge parity
  a0 += __shfl_xor(a0, 16);
  a1 += __shfl_xor(a1, 16);
  a2 += __shfl_xor(a2, 16);
  a3 += __shfl_xor(a3, 16);

  // ---- fused finalize ----
  const float rden = 1.f / (den + 1e-16f);
  float v0 = a0 * rden + bv.x;
  float v1 = a1 * rden + bv.y;
  float v2 = a2 * rden + bv.z;
  float v3 = a3 * rden + bv.w;
  if (conv == 0) {
    v0 = fmaxf(v0, 0.f);
    v1 = fmaxf(v1, 0.f);
    v2 = fmaxf(v2, 0.f);
    v3 = fmaxf(v3, 0.f);
  }
  v0 += xr4.x; v1 += xr4.y; v2 += xr4.z; v3 += xr4.w;
  const float v64 = o64 + x64v;

  float mx = fmaxf(fmaxf(v0, v1), fmaxf(v2, v3));
  #pragma unroll
  for (int off = 1; off < 16; off <<= 1) mx = fmaxf(mx, __shfl_xor(mx, off));
  mx = fmaxf(mx, v64);
  float sm = __expf(v0 - mx) + __expf(v1 - mx) + __expf(v2 - mx) + __expf(v3 - mx);
  #pragma unroll
  for (int off = 1; off < 16; off <<= 1) sm += __shfl_xor(sm, off);
  sm += __expf(v64 - mx);
  const float ls = __logf(sm);

  if (eg == 0) {
    *(float4*)&row[ch] = make_float4(v0 - mx - ls, v1 - mx - ls, v2 - mx - ls, v3 - mx - ls);
    if (hl == 0) row[64] = v64 - mx - ls;
  }
}

// ---------------------------------------------------------------------------
extern "C" void kernel_launch(void* const* d_in, const int* in_sizes, int n_in,
                              void* d_out, int out_size, void* d_ws, size_t ws_size,
                              hipStream_t stream)
{
  const float* x    = (const float*)d_in[0];
  const int*   ei   = (const int*)d_in[1];
  const float* Wmlp = (const float*)d_in[2];
  const float* bmlp = (const float*)d_in[3];
  const float* W1   = (const float*)d_in[4];
  const float* a1s  = (const float*)d_in[5];
  const float* a1d  = (const float*)d_in[6];
  const float* b1   = (const float*)d_in[7];
  const float* W2   = (const float*)d_in[8];
  const float* a2s  = (const float*)d_in[9];
  const float* a2d  = (const float*)d_in[10];
  const float* b2   = (const float*)d_in[11];
  float* out = (float*)d_out;

  unsigned char* hb8 = (unsigned char*)d_ws;             // NN*64 fp8 (6.4 MB)
  float* sd2 = (float*)(hb8 + (size_t)NN * 64);          // 2*NN
  float* dd2 = sd2 + (size_t)2 * NN;                     // 2*NN
  int* ebuf   = (int*)(dd2 + (size_t)2 * NN);            // NE (6.4 MB, chunk-major sorted)
  int* csrc   = ebuf + NE;                               // NBUCK*ESTRIDE (8 MB)
  int* rpp    = csrc + (size_t)NBUCK * ESTRIDE;          // NBUCK*256
  int* cntT   = rpp + NBUCK * 256;                       // CHUNKS*NBUCK
  int* offT   = cntT + CHUNKS * NBUCK;                   // CHUNKS*NBUCK
  short* wbg  = (short*)(offT + CHUNKS * NBUCK);         // 16384 bf16

  k_prep<<<32, 256, 0, stream>>>(Wmlp, W1, W2, wbg);

  k_main<<<NODE_BLOCKS + CHUNKS, 256, 0, stream>>>(
      x, wbg, Wmlp, bmlp, a1s, a1d, a2s, a2d, ei,
      hb8, sd2, dd2, out, ebuf, cntT, offT);

  k_csr<<<NBUCK, 256, 0, stream>>>(cntT, offT, ebuf, rpp, csrc);

  k_conv<<<NN / 8, 256, 0, stream>>>(rpp, csrc, hb8, sd2, dd2, x, b1, b2, out);
}